// Round 4
// baseline (4336.908 us; speedup 1.0000x reference)
//
#include <hip/hip_runtime.h>
#include <hip/hip_bf16.h>

typedef short  bf16x8 __attribute__((ext_vector_type(8)));
typedef float  f32x4  __attribute__((ext_vector_type(4)));
typedef int    i32x2  __attribute__((ext_vector_type(2)));

#define BB 64
#define SS 512
#define EE 300
#define HH 512

// workspace layout (bytes)
#define XT_OFF     ((size_t)0)
#define XT_BYTES   ((size_t)SS*10*4*1024)        // 20,971,520  x tiles [t][ks10][mt4][1KB]
#define HBUF_OFF   (XT_OFF + XT_BYTES)
#define HBUF_BYTES ((size_t)2*16*4*1024)         // 131,072: 2 x fragment-tiled [ks16][mt4][1KB]
#define HT_OFF     (HBUF_OFF + HBUF_BYTES)
#define HT_BYTES   ((size_t)BB*HH*4)             // 131,072
#define CNT_OFF    (HT_OFF + HT_BYTES)
#define CNT_BYTES  ((size_t)256)

__device__ __forceinline__ unsigned short f2bf(float x) {
  union { float f; unsigned u; } v; v.f = x;
  unsigned r = v.u + 0x7fffu + ((v.u >> 16) & 1u);   // RNE
  return (unsigned short)(r >> 16);
}
__device__ __forceinline__ float sigm(float x) { return 1.f / (1.f + __expf(-x)); }
__device__ __forceinline__ float tanh_fast(float x) { return 1.f - 2.f / (__expf(2.f * x) + 1.f); }

// ---- coherent (bypass L1/L2, served at Infinity Cache) primitives ----
__device__ __forceinline__ void ld16_cc(bf16x8* dst, const void* p) {
  asm volatile("global_load_dwordx4 %0, %1, off sc0 sc1"
               : "=v"(*dst) : "v"(p) : "memory");
}
__device__ __forceinline__ int ld_flag_cc(const int* p) {
  int r;
  asm volatile("global_load_dword %0, %1, off sc0 sc1\n\ts_waitcnt vmcnt(0)"
               : "=v"(r) : "v"(p) : "memory");
  return r;
}
__device__ __forceinline__ void st8_cc(void* p, i32x2 v) {
  asm volatile("global_store_dwordx2 %0, %1, off sc0 sc1"
               :: "v"(p), "v"(v) : "memory");
}

// ---- phase 0: embedding gather + cast, fragment-tiled output ----
// block layout: [t][ks(10)][mtile(4)] of 1KB; within block [c(16)][kg(4)][j(8)] bf16
__global__ void gather_cast_kernel(const int* __restrict__ idx,
                                   const float* __restrict__ emb,
                                   unsigned short* __restrict__ xt) {
  __shared__ unsigned short lds_x[16 * 320];
  const int t     = blockIdx.x >> 2;
  const int mtile = blockIdx.x & 3;
  const int tid   = threadIdx.x;                 // 0..255

  const int c2 = tid >> 4;
  const int e0 = tid & 15;
  const int b  = mtile * 16 + c2;
  const int vocab = idx[b * SS + t];
  const float* src = emb + (size_t)vocab * EE;
  for (int e = e0; e < 320; e += 16)
    lds_x[c2 * 320 + e] = (e < EE) ? f2bf(src[e]) : (unsigned short)0;
  __syncthreads();

  unsigned short* outb = xt + (((size_t)t * 10) * 4 + mtile) * 512;
  #pragma unroll
  for (int rr = 0; rr < 3; ++rr) {
    int O = rr * 4096 + tid * 16;                // byte offset within 10KB
    if (O < 10240) {
      int ks = O >> 10;
      int inblk = O & 1023;
      int c  = inblk >> 6;
      int kg = (inblk >> 4) & 3;
      bf16x8 v = *(const bf16x8*)&lds_x[c * 320 + ks * 32 + kg * 8];
      *(bf16x8*)((char*)outb + (size_t)ks * 4096 + inblk) = v;
    }
  }
}

// ---- phase 1: persistent recurrence, fully wave-decoupled ----
// wg p owns hidden units [8p,8p+8). 8 waves = 4 m-tiles x 2 unit-halves.
// W in VGPRs. h stored in fragment-tiled layout -> direct coalesced MFMA loads.
// No __syncthreads in the loop; publish via LDS-counter + one agent atomic.
__launch_bounds__(512, 2)
__global__ void lstm_kernel(const unsigned short* __restrict__ xt,
                            unsigned short* __restrict__ hbuf,   // [2][ks16][mt4][1KB]
                            float* __restrict__ hT,              // [BB][HH] fp32
                            int* __restrict__ cnt,               // central counter
                            const float* __restrict__ Wih,
                            const float* __restrict__ Whh,
                            const float* __restrict__ bih,
                            const float* __restrict__ bhh) {
  __shared__ int lds_cnt;

  const int p    = blockIdx.x;             // 0..63
  const int tid  = threadIdx.x;            // 0..511
  const int l    = tid & 63;
  const int w    = tid >> 6;               // 0..7
  const int mt   = w & 3;                  // m-tile: samples 16mt..16mt+15
  const int nt   = w >> 2;                 // unit-half: units 4nt..4nt+3
  const int c    = l & 15;                 // B col: gate=c>>2, unit=c&3
  const int kg   = l >> 4;                 // k-group

  if (tid == 0) lds_cnt = 0;
  __syncthreads();

  // ---- preload W fragments (constant all 512 steps) ----
  const int Grow = ((c >> 2) << 9) + (p << 3) + (nt << 2) + (c & 3);
  const float* wih_row = Wih + (size_t)Grow * EE;
  const float* whh_row = Whh + (size_t)Grow * HH;

  bf16x8 Bx[10], Bh[16];
  #pragma unroll
  for (int ks = 0; ks < 10; ++ks) {
    int k0 = 32 * ks + 8 * kg;
    bf16x8 vb;
    #pragma unroll
    for (int j = 0; j < 8; ++j) {
      int k = k0 + j;
      vb[j] = (short)((k < EE) ? f2bf(wih_row[k]) : (unsigned short)0);
    }
    Bx[ks] = vb;
  }
  #pragma unroll
  for (int ks = 0; ks < 16; ++ks) {
    int k0 = 32 * ks + 8 * kg;
    bf16x8 vb;
    #pragma unroll
    for (int j = 0; j < 8; ++j) vb[j] = (short)f2bf(whh_row[k0 + j]);
    Bh[ks] = vb;
  }
  const float bsum = bih[Grow] + bhh[Grow];

  // x fragment offset within a 1KB block
  const int xoff = (c << 5) + (kg << 3);           // ushort units
  // h fragment read offset within a 1KB block (bytes)
  const int frag_in = (c << 6) + (kg << 4);
  // h store: block row = p>>2, inblock byte = ((4kg+r)<<6) | ((p&3)<<4) | (nt<<3)
  const int st_in = ((p & 3) << 4) + (nt << 3);

  f32x4 cst = {0.f, 0.f, 0.f, 0.f};

  for (int it = 0; it < SS; ++it) {
    f32x4 acc  = {0.f, 0.f, 0.f, 0.f};
    f32x4 acc2 = {0.f, 0.f, 0.f, 0.f};

    // --- x part (plain cached loads, coalesced 1KB per instr) ---
    const unsigned short* xq = xt + (((size_t)it * 10) * 4 + mt) * 512 + xoff;
    #pragma unroll
    for (int ks = 0; ks < 10; ks += 2) {
      bf16x8 a0 = *(const bf16x8*)(xq + (size_t)ks * 2048);
      bf16x8 a1 = *(const bf16x8*)(xq + (size_t)(ks + 1) * 2048);
      acc  = __builtin_amdgcn_mfma_f32_16x16x32_bf16(a0, Bx[ks],     acc,  0, 0, 0);
      acc2 = __builtin_amdgcn_mfma_f32_16x16x32_bf16(a1, Bx[ks + 1], acc2, 0, 0, 0);
    }

    // --- wait for h(it): every wave polls (64 lanes, 1 addr = 1 transaction) ---
    if (it > 0) {
      const int target = 64 * it;
      while (ld_flag_cc(cnt) < target) __builtin_amdgcn_s_sleep(1);
    }

    // --- h part: 16 coalesced coherent fragment loads -> MFMA direct ---
    const char* hp = (const char*)hbuf + (size_t)(it & 1) * 65536 + frag_in;
    bf16x8 ha[16];
    #pragma unroll
    for (int ks = 0; ks < 16; ++ks)
      ld16_cc(&ha[ks], hp + (((size_t)(ks << 2) + mt) << 10));

    asm volatile("s_waitcnt vmcnt(8)" ::: "memory");
    __builtin_amdgcn_sched_barrier(0);
    #pragma unroll
    for (int ks = 0; ks < 8; ks += 2) {
      acc  = __builtin_amdgcn_mfma_f32_16x16x32_bf16(ha[ks],     Bh[ks],     acc,  0, 0, 0);
      acc2 = __builtin_amdgcn_mfma_f32_16x16x32_bf16(ha[ks + 1], Bh[ks + 1], acc2, 0, 0, 0);
    }
    asm volatile("s_waitcnt vmcnt(0)" ::: "memory");
    __builtin_amdgcn_sched_barrier(0);
    #pragma unroll
    for (int ks = 8; ks < 16; ks += 2) {
      acc  = __builtin_amdgcn_mfma_f32_16x16x32_bf16(ha[ks],     Bh[ks],     acc,  0, 0, 0);
      acc2 = __builtin_amdgcn_mfma_f32_16x16x32_bf16(ha[ks + 1], Bh[ks + 1], acc2, 0, 0, 0);
    }
    acc += acc2;

    // --- gate math in-register; h stored in fragment layout ---
    char* hw = (char*)hbuf + (size_t)((it + 1) & 1) * 65536;
    #pragma unroll
    for (int r = 0; r < 4; ++r) {
      float v  = acc[r] + bsum;
      float vf = __shfl_xor(v, 4, 64);
      float vg = __shfl_xor(v, 8, 64);
      float vo = __shfl_xor(v, 12, 64);
      float ig = sigm(v);
      float fg = sigm(vf);
      float gt = tanh_fast(vg);
      float og = sigm(vo);
      float cc_ = fg * cst[r] + ig * gt;
      cst[r] = cc_;
      float h = og * tanh_fast(cc_);

      int v0 = (int)f2bf(h);
      int o1 = __shfl_xor(v0, 1, 64);
      int pk = (v0 & 0xffff) | (o1 << 16);
      int o2 = __shfl_xor(pk, 2, 64);
      if (c == 0) {
        i32x2 val; val[0] = pk; val[1] = o2;
        // block = (p>>2)*4 + mt ; inblock = ((4kg+r)<<6) | st_in
        char* dst = hw + ((((size_t)(p >> 2) << 2) + mt) << 10)
                       + (((kg << 2) + r) << 6) + st_in;
        st8_cc(dst, val);
      }
      if (it == SS - 1 && c < 4) {
        int s = 16 * mt + 4 * kg + r;
        hT[(size_t)s * HH + (p << 3) + (nt << 2) + c] = h;
      }
    }

    // --- publish: drain own stores, per-wave LDS count, 8th does agent atomic ---
    asm volatile("s_waitcnt vmcnt(0)" ::: "memory");
    if (l == 0) {
      int old = __hip_atomic_fetch_add(&lds_cnt, 1, __ATOMIC_RELAXED,
                                       __HIP_MEMORY_SCOPE_WORKGROUP);
      if (old == 8 * it + 7)
        __hip_atomic_fetch_add(cnt, 1, __ATOMIC_RELAXED, __HIP_MEMORY_SCOPE_AGENT);
    }
  }
}

// ---- phase 2: y[b] = hT[b,:] . Wout + bout ----
__global__ void outproj_kernel(const float* __restrict__ hT,
                               const float* __restrict__ Wout,
                               const float* __restrict__ bout,
                               float* __restrict__ y) {
  int b = blockIdx.x;
  int t = threadIdx.x;   // 64
  float s = 0.f;
  for (int j = t; j < HH; j += 64) s += hT[b * HH + j] * Wout[j];
  #pragma unroll
  for (int off = 32; off > 0; off >>= 1) s += __shfl_down(s, off, 64);
  if (t == 0) y[b] = s + bout[0];
}

extern "C" void kernel_launch(void* const* d_in, const int* in_sizes, int n_in,
                              void* d_out, int out_size, void* d_ws, size_t ws_size,
                              hipStream_t stream) {
  const int*   idx  = (const int*)d_in[0];
  const float* emb  = (const float*)d_in[1];
  const float* Wih  = (const float*)d_in[2];
  const float* Whh  = (const float*)d_in[3];
  const float* bih  = (const float*)d_in[4];
  const float* bhh  = (const float*)d_in[5];
  const float* Wout = (const float*)d_in[6];
  const float* bout = (const float*)d_in[7];
  float* y = (float*)d_out;

  char* ws = (char*)d_ws;
  unsigned short* xt   = (unsigned short*)(ws + XT_OFF);
  unsigned short* hbuf = (unsigned short*)(ws + HBUF_OFF);
  float* hT            = (float*)(ws + HT_OFF);
  int* cnt             = (int*)(ws + CNT_OFF);

  // deterministic per-call init: h(0)=0 (buffer 0) and cnt=0
  hipMemsetAsync(ws + HBUF_OFF, 0, (size_t)65536, stream);
  hipMemsetAsync(ws + CNT_OFF, 0, CNT_BYTES, stream);

  gather_cast_kernel<<<SS * 4, 256, 0, stream>>>(idx, emb, xt);
  lstm_kernel<<<64, 512, 0, stream>>>(xt, hbuf, hT, cnt, Wih, Whh, bih, bhh);
  outproj_kernel<<<BB, 64, 0, stream>>>(hT, Wout, bout, y);
}

// Round 5
// 2678.555 us; speedup vs baseline: 1.6191x; 1.6191x over previous
//
#include <hip/hip_runtime.h>
#include <hip/hip_bf16.h>

typedef short  bf16x8 __attribute__((ext_vector_type(8)));
typedef float  f32x4  __attribute__((ext_vector_type(4)));
typedef int    i32x2  __attribute__((ext_vector_type(2)));

#define BB 64
#define SS 512
#define EE 300
#define HH 512

// workspace layout (bytes)
#define XT_OFF     ((size_t)0)
#define XT_BYTES   ((size_t)SS*10*4*1024)        // 20,971,520  x tiles [t][ks10][mt4][1KB]
#define HBUF_OFF   (XT_OFF + XT_BYTES)
#define HBUF_BYTES ((size_t)2*16*4*1024)         // 131,072: 2 x fragment-tiled [ks16][mt4][1KB]
#define HT_OFF     (HBUF_OFF + HBUF_BYTES)
#define HT_BYTES   ((size_t)BB*HH*4)             // 131,072
#define FLAGS_OFF  (HT_OFF + HT_BYTES)
#define FLAGS_BYTES ((size_t)256)                // flags[64]

__device__ __forceinline__ unsigned short f2bf(float x) {
  union { float f; unsigned u; } v; v.f = x;
  unsigned r = v.u + 0x7fffu + ((v.u >> 16) & 1u);   // RNE
  return (unsigned short)(r >> 16);
}
__device__ __forceinline__ float sigm(float x) { return 1.f / (1.f + __expf(-x)); }
__device__ __forceinline__ float tanh_fast(float x) { return 1.f - 2.f / (__expf(2.f * x) + 1.f); }

// ---- coherent (bypass L1/L2, served at Infinity Cache) primitives ----
__device__ __forceinline__ void ld16_cc(bf16x8* dst, const void* p) {
  asm volatile("global_load_dwordx4 %0, %1, off sc0 sc1"
               : "=v"(*dst) : "v"(p) : "memory");
}
__device__ __forceinline__ int ld_flag_cc(const int* p) {
  int r;
  asm volatile("global_load_dword %0, %1, off sc0 sc1\n\ts_waitcnt vmcnt(0)"
               : "=v"(r) : "v"(p) : "memory");
  return r;
}
__device__ __forceinline__ void st8_cc(void* p, i32x2 v) {
  asm volatile("global_store_dwordx2 %0, %1, off sc0 sc1"
               :: "v"(p), "v"(v) : "memory");
}
__device__ __forceinline__ void st4_cc(void* p, int v) {
  asm volatile("global_store_dword %0, %1, off sc0 sc1"
               :: "v"(p), "v"(v) : "memory");
}

// ---- phase 0: embedding gather + cast, fragment-tiled output ----
// block layout: [t][ks(10)][mtile(4)] of 1KB; within block [c(16)][kg(4)][j(8)] bf16
__global__ void gather_cast_kernel(const int* __restrict__ idx,
                                   const float* __restrict__ emb,
                                   unsigned short* __restrict__ xt) {
  __shared__ unsigned short lds_x[16 * 320];
  const int t     = blockIdx.x >> 2;
  const int mtile = blockIdx.x & 3;
  const int tid   = threadIdx.x;                 // 0..255

  const int c2 = tid >> 4;
  const int e0 = tid & 15;
  const int b  = mtile * 16 + c2;
  const int vocab = idx[b * SS + t];
  const float* src = emb + (size_t)vocab * EE;
  for (int e = e0; e < 320; e += 16)
    lds_x[c2 * 320 + e] = (e < EE) ? f2bf(src[e]) : (unsigned short)0;
  __syncthreads();

  unsigned short* outb = xt + (((size_t)t * 10) * 4 + mtile) * 512;
  #pragma unroll
  for (int rr = 0; rr < 3; ++rr) {
    int O = rr * 4096 + tid * 16;                // byte offset within 10KB
    if (O < 10240) {
      int ks = O >> 10;
      int inblk = O & 1023;
      int c  = inblk >> 6;
      int kg = (inblk >> 4) & 3;
      bf16x8 v = *(const bf16x8*)&lds_x[c * 320 + ks * 32 + kg * 8];
      *(bf16x8*)((char*)outb + (size_t)ks * 4096 + inblk) = v;
    }
  }
}

// ---- phase 1: persistent recurrence. wg p owns hidden units [8p,8p+8). ----
// 8 waves = 4 m-tiles x 2 unit-halves. W in VGPRs. h in fragment-tiled layout.
// Sync: store-only flags[64]; wave 0 polls (one 4-line load), barrier releases.
__launch_bounds__(512, 2)
__global__ void lstm_kernel(const unsigned short* __restrict__ xt,
                            unsigned short* __restrict__ hbuf,   // [2][ks16][mt4][1KB]
                            float* __restrict__ hT,              // [BB][HH] fp32
                            int* __restrict__ flags,             // [64]
                            const float* __restrict__ Wih,
                            const float* __restrict__ Whh,
                            const float* __restrict__ bih,
                            const float* __restrict__ bhh) {
  const int p    = blockIdx.x;             // 0..63
  const int tid  = threadIdx.x;            // 0..511
  const int l    = tid & 63;
  const int w    = tid >> 6;               // 0..7
  const int mt   = w & 3;                  // m-tile: samples 16mt..16mt+15
  const int nt   = w >> 2;                 // unit-half: units 4nt..4nt+3
  const int c    = l & 15;                 // B col: gate=c>>2, unit=c&3
  const int kg   = l >> 4;                 // k-group

  // ---- preload W fragments (constant all 512 steps) ----
  const int Grow = ((c >> 2) << 9) + (p << 3) + (nt << 2) + (c & 3);
  const float* wih_row = Wih + (size_t)Grow * EE;
  const float* whh_row = Whh + (size_t)Grow * HH;

  bf16x8 Bx[10], Bh[16];
  #pragma unroll
  for (int ks = 0; ks < 10; ++ks) {
    int k0 = 32 * ks + 8 * kg;
    bf16x8 vb;
    #pragma unroll
    for (int j = 0; j < 8; ++j) {
      int k = k0 + j;
      vb[j] = (short)((k < EE) ? f2bf(wih_row[k]) : (unsigned short)0);
    }
    Bx[ks] = vb;
  }
  #pragma unroll
  for (int ks = 0; ks < 16; ++ks) {
    int k0 = 32 * ks + 8 * kg;
    bf16x8 vb;
    #pragma unroll
    for (int j = 0; j < 8; ++j) vb[j] = (short)f2bf(whh_row[k0 + j]);
    Bh[ks] = vb;
  }
  const float bsum = bih[Grow] + bhh[Grow];

  // x fragment offset within a 1KB block (ushort units)
  const int xoff = (c << 5) + (kg << 3);
  // h fragment read offset within a 1KB block (bytes)
  const int frag_in = (c << 6) + (kg << 4);
  // h store: in-block byte pieces
  const int st_in = ((p & 3) << 4) + (nt << 3);

  f32x4 cst = {0.f, 0.f, 0.f, 0.f};

  for (int it = 0; it < SS; ++it) {
    f32x4 acc  = {0.f, 0.f, 0.f, 0.f};
    f32x4 acc2 = {0.f, 0.f, 0.f, 0.f};

    // --- x part (plain cached loads, coalesced 1KB per instr; overlaps wait) ---
    const unsigned short* xq = xt + (((size_t)it * 10) * 4 + mt) * 512 + xoff;
    #pragma unroll
    for (int ks = 0; ks < 10; ks += 2) {
      bf16x8 a0 = *(const bf16x8*)(xq + (size_t)ks * 2048);
      bf16x8 a1 = *(const bf16x8*)(xq + (size_t)(ks + 1) * 2048);
      acc  = __builtin_amdgcn_mfma_f32_16x16x32_bf16(a0, Bx[ks],     acc,  0, 0, 0);
      acc2 = __builtin_amdgcn_mfma_f32_16x16x32_bf16(a1, Bx[ks + 1], acc2, 0, 0, 0);
    }

    // --- wait for h(it): wave 0 polls flags[0..63] (4 lines), barrier releases ---
    if (it > 0) {
      if (w == 0) {
        for (;;) {
          int f = ld_flag_cc(flags + l);
          if (__all(f >= it)) break;
        }
      }
      __syncthreads();
    }

    // --- h part: 16 coalesced coherent fragment loads -> MFMA direct ---
    const char* hp = (const char*)hbuf + (size_t)(it & 1) * 65536 + frag_in;
    bf16x8 ha[16];
    #pragma unroll
    for (int ks = 0; ks < 16; ++ks)
      ld16_cc(&ha[ks], hp + (((size_t)(ks << 2) + mt) << 10));

    asm volatile("s_waitcnt vmcnt(8)" ::: "memory");
    __builtin_amdgcn_sched_barrier(0);
    #pragma unroll
    for (int ks = 0; ks < 8; ks += 2) {
      acc  = __builtin_amdgcn_mfma_f32_16x16x32_bf16(ha[ks],     Bh[ks],     acc,  0, 0, 0);
      acc2 = __builtin_amdgcn_mfma_f32_16x16x32_bf16(ha[ks + 1], Bh[ks + 1], acc2, 0, 0, 0);
    }
    asm volatile("s_waitcnt vmcnt(0)" ::: "memory");
    __builtin_amdgcn_sched_barrier(0);
    #pragma unroll
    for (int ks = 8; ks < 16; ks += 2) {
      acc  = __builtin_amdgcn_mfma_f32_16x16x32_bf16(ha[ks],     Bh[ks],     acc,  0, 0, 0);
      acc2 = __builtin_amdgcn_mfma_f32_16x16x32_bf16(ha[ks + 1], Bh[ks + 1], acc2, 0, 0, 0);
    }
    acc += acc2;

    // --- gate math in-register; h stored in fragment layout ---
    char* hw = (char*)hbuf + (size_t)((it + 1) & 1) * 65536;
    #pragma unroll
    for (int r = 0; r < 4; ++r) {
      float v  = acc[r] + bsum;
      float vf = __shfl_xor(v, 4, 64);
      float vg = __shfl_xor(v, 8, 64);
      float vo = __shfl_xor(v, 12, 64);
      float ig = sigm(v);
      float fg = sigm(vf);
      float gt = tanh_fast(vg);
      float og = sigm(vo);
      float cc_ = fg * cst[r] + ig * gt;
      cst[r] = cc_;
      float h = og * tanh_fast(cc_);

      int v0 = (int)f2bf(h);
      int o1 = __shfl_xor(v0, 1, 64);
      int pk = (v0 & 0xffff) | (o1 << 16);
      int o2 = __shfl_xor(pk, 2, 64);
      if (c == 0) {
        i32x2 val; val[0] = pk; val[1] = o2;
        char* dst = hw + ((((size_t)(p >> 2) << 2) + mt) << 10)
                       + (((kg << 2) + r) << 6) + st_in;
        st8_cc(dst, val);
      }
      if (it == SS - 1 && c < 4) {
        int s = 16 * mt + 4 * kg + r;
        hT[(size_t)s * HH + (p << 3) + (nt << 2) + c] = h;
      }
    }

    // --- publish: drain own stores, barrier, single flag store (no RMW) ---
    asm volatile("s_waitcnt vmcnt(0)" ::: "memory");
    __syncthreads();
    if (tid == 0) st4_cc(flags + p, it + 1);
  }
}

// ---- phase 2: y[b] = hT[b,:] . Wout + bout ----
__global__ void outproj_kernel(const float* __restrict__ hT,
                               const float* __restrict__ Wout,
                               const float* __restrict__ bout,
                               float* __restrict__ y) {
  int b = blockIdx.x;
  int t = threadIdx.x;   // 64
  float s = 0.f;
  for (int j = t; j < HH; j += 64) s += hT[b * HH + j] * Wout[j];
  #pragma unroll
  for (int off = 32; off > 0; off >>= 1) s += __shfl_down(s, off, 64);
  if (t == 0) y[b] = s + bout[0];
}

extern "C" void kernel_launch(void* const* d_in, const int* in_sizes, int n_in,
                              void* d_out, int out_size, void* d_ws, size_t ws_size,
                              hipStream_t stream) {
  const int*   idx  = (const int*)d_in[0];
  const float* emb  = (const float*)d_in[1];
  const float* Wih  = (const float*)d_in[2];
  const float* Whh  = (const float*)d_in[3];
  const float* bih  = (const float*)d_in[4];
  const float* bhh  = (const float*)d_in[5];
  const float* Wout = (const float*)d_in[6];
  const float* bout = (const float*)d_in[7];
  float* y = (float*)d_out;

  char* ws = (char*)d_ws;
  unsigned short* xt   = (unsigned short*)(ws + XT_OFF);
  unsigned short* hbuf = (unsigned short*)(ws + HBUF_OFF);
  float* hT            = (float*)(ws + HT_OFF);
  int* flags           = (int*)(ws + FLAGS_OFF);

  // deterministic per-call init: h(0)=0 (buffer 0) and flags=0
  hipMemsetAsync(ws + HBUF_OFF, 0, (size_t)65536, stream);
  hipMemsetAsync(ws + FLAGS_OFF, 0, FLAGS_BYTES, stream);

  gather_cast_kernel<<<SS * 4, 256, 0, stream>>>(idx, emb, xt);
  lstm_kernel<<<64, 512, 0, stream>>>(xt, hbuf, hT, flags, Wih, Whh, bih, bhh);
  outproj_kernel<<<BB, 64, 0, stream>>>(hT, Wout, bout, y);
}

// Round 6
// 1940.927 us; speedup vs baseline: 2.2345x; 1.3800x over previous
//
#include <hip/hip_runtime.h>
#include <hip/hip_bf16.h>

typedef short  bf16x8 __attribute__((ext_vector_type(8)));
typedef float  f32x4  __attribute__((ext_vector_type(4)));
typedef int    i32x4  __attribute__((ext_vector_type(4)));

#define BB 64
#define SS 512
#define EE 300
#define HH 512

// workspace layout (bytes)
#define XT_OFF     ((size_t)0)
#define XT_BYTES   ((size_t)SS*10*4*1024)        // 20,971,520  x tiles [t][ks10][mt4][1KB]
#define SLOT_OFF   (XT_OFF + XT_BYTES)
#define SLOT_BYTES ((size_t)2*64*2*64*16)        // 262,144: [plane2][q64][j2][s64] 16B tagged slots
#define HT_OFF     (SLOT_OFF + SLOT_BYTES)
#define HT_BYTES   ((size_t)BB*HH*4)             // 131,072

__device__ __forceinline__ unsigned short f2bf(float x) {
  union { float f; unsigned u; } v; v.f = x;
  unsigned r = v.u + 0x7fffu + ((v.u >> 16) & 1u);   // RNE
  return (unsigned short)(r >> 16);
}
__device__ __forceinline__ float sigm(float x) { return 1.f / (1.f + __expf(-x)); }
__device__ __forceinline__ float tanh_fast(float x) { return 1.f - 2.f / (__expf(2.f * x) + 1.f); }

// ---- coherent (bypass L1/L2, served at Infinity Cache) primitives ----
__device__ __forceinline__ void ld16_cc(i32x4* dst, const void* p) {
  asm volatile("global_load_dwordx4 %0, %1, off sc0 sc1"
               : "=v"(*dst) : "v"(p) : "memory");
}
__device__ __forceinline__ void st16_cc(void* p, i32x4 v) {
  asm volatile("global_store_dwordx4 %0, %1, off sc0 sc1"
               :: "v"(p), "v"(v) : "memory");
}

// ---- phase 0: embedding gather + cast, fragment-tiled output ----
// block layout: [t][ks(10)][mtile(4)] of 1KB; within block [c(16)][kg(4)][j(8)] bf16
__global__ void gather_cast_kernel(const int* __restrict__ idx,
                                   const float* __restrict__ emb,
                                   unsigned short* __restrict__ xt) {
  __shared__ unsigned short lds_x[16 * 320];
  const int t     = blockIdx.x >> 2;
  const int mtile = blockIdx.x & 3;
  const int tid   = threadIdx.x;                 // 0..255

  const int c2 = tid >> 4;
  const int e0 = tid & 15;
  const int b  = mtile * 16 + c2;
  const int vocab = idx[b * SS + t];
  const float* src = emb + (size_t)vocab * EE;
  for (int e = e0; e < 320; e += 16)
    lds_x[c2 * 320 + e] = (e < EE) ? f2bf(src[e]) : (unsigned short)0;
  __syncthreads();

  unsigned short* outb = xt + (((size_t)t * 10) * 4 + mtile) * 512;
  #pragma unroll
  for (int rr = 0; rr < 3; ++rr) {
    int O = rr * 4096 + tid * 16;                // byte offset within 10KB
    if (O < 10240) {
      int ks = O >> 10;
      int inblk = O & 1023;
      int c  = inblk >> 6;
      int kg = (inblk >> 4) & 3;
      bf16x8 v = *(const bf16x8*)&lds_x[c * 320 + ks * 32 + kg * 8];
      *(bf16x8*)((char*)outb + (size_t)ks * 4096 + inblk) = v;
    }
  }
}

// ---- phase 1: persistent recurrence with tagged-slot sync ----
// wg p owns hidden units [8p,8p+8). 8 waves = (mt in 0..3) x (kh in 0..1).
// MFMA phase: wave (mt,kh) computes partial gates for samples 16mt..+15,
//   all 32 gate-cols (8 units x 4 gates), K-half kh. h is read as tagged
//   16B slots {8B data, 4B tag, 4B pad}: the load IS the sync.
// LDS exchange sums K-halves; finalize is split by sample: lane=(s&7)*8+u
//   owns (sample, unit) with scalar cell state, stores tagged slots.
__launch_bounds__(512)
__global__ void lstm_kernel(const unsigned short* __restrict__ xt,
                            char* __restrict__ slots,            // [2][64][2][64]*16B
                            float* __restrict__ hT,              // [BB][HH] fp32
                            const float* __restrict__ Wih,
                            const float* __restrict__ Whh,
                            const float* __restrict__ bih,
                            const float* __restrict__ bhh) {
  __shared__ float glds[2][2][64][33];     // [buf][kh][sample][gate*8+unit], padded

  const int p    = blockIdx.x;             // 0..63
  const int tid  = threadIdx.x;            // 0..511
  const int l    = tid & 63;
  const int w    = tid >> 6;               // 0..7
  const int mt   = w & 3;                  // m-tile: samples 16mt..16mt+15
  const int kh   = w >> 2;                 // K-half (x: ks 5kh..; h: ks 8kh..)
  const int c    = l & 15;                 // B col within tile
  const int kg   = l >> 4;                 // k-group

  // ---- preload W fragments (constant all 512 steps) ----
  // tile T covers units 4T..4T+3; col c: gate=c>>2, unit=4T+(c&3)
  bf16x8 Bx[2][5], Bh[2][8];
  #pragma unroll
  for (int T = 0; T < 2; ++T) {
    const int Grow = ((c >> 2) << 9) + (p << 3) + (T << 2) + (c & 3);
    const float* wih_row = Wih + (size_t)Grow * EE;
    const float* whh_row = Whh + (size_t)Grow * HH;
    #pragma unroll
    for (int ks = 0; ks < 5; ++ks) {
      int k0 = 32 * (5 * kh + ks) + 8 * kg;
      bf16x8 vb;
      #pragma unroll
      for (int j = 0; j < 8; ++j) {
        int k = k0 + j;
        vb[j] = (short)((k < EE) ? f2bf(wih_row[k]) : (unsigned short)0);
      }
      Bx[T][ks] = vb;
    }
    #pragma unroll
    for (int ks = 0; ks < 8; ++ks) {
      int k0 = 32 * (8 * kh + ks) + 8 * kg;
      bf16x8 vb;
      #pragma unroll
      for (int j = 0; j < 8; ++j) vb[j] = (short)f2bf(whh_row[k0 + j]);
      Bh[T][ks] = vb;
    }
  }

  // finalize-lane mapping: lane = (s&7)*8 + u
  const int u     = l & 7;
  const int sl    = l >> 3;
  const int sglob = 16 * mt + 8 * kh + sl;
  const float bi  = bih[(p << 3) + u]        + bhh[(p << 3) + u];
  const float bf_ = bih[512  + (p << 3) + u] + bhh[512  + (p << 3) + u];
  const float bg  = bih[1024 + (p << 3) + u] + bhh[1024 + (p << 3) + u];
  const float bo  = bih[1536 + (p << 3) + u] + bhh[1536 + (p << 3) + u];
  float cstate = 0.f;

  // x base: blocks ((it*10 + 5kh+ks)*4 + mt), inblock (c,kg)
  const unsigned short* xbase = xt + ((size_t)(5 * kh) * 4 + mt) * 512
                                   + (c << 5) + (kg << 3);
  // slot read base: q = 32kh + 4ks' + kg, sample = 16mt + c
  const int rd_in = ((32 * kh + kg) << 11) + ((16 * mt + c) << 4);
  // slot write base pieces (lanes u in {0,4} store j = u>>2)
  char* const wr_base = slots + ((size_t)p << 11) + (((size_t)(u >> 2)) << 10)
                              + ((size_t)sglob << 4);
  const int colp = ((c >> 2) << 3) + (c & 3);

  for (int it = 0; it < SS; ++it) {
    f32x4 acc0 = {0.f, 0.f, 0.f, 0.f};
    f32x4 acc1 = {0.f, 0.f, 0.f, 0.f};

    // --- x part: 5 fragments x 2 col-tiles (cached loads, off critical path) ---
    const unsigned short* xp = xbase + (size_t)it * 20480;
    #pragma unroll
    for (int ks = 0; ks < 5; ++ks) {
      bf16x8 a = *(const bf16x8*)(xp + (size_t)ks * 2048);
      acc0 = __builtin_amdgcn_mfma_f32_16x16x32_bf16(a, Bx[0][ks], acc0, 0, 0, 0);
      acc1 = __builtin_amdgcn_mfma_f32_16x16x32_bf16(a, Bx[1][ks], acc1, 0, 0, 0);
    }

    // --- h part: tagged-slot poll-load (the load IS the sync) ---
    const char* rp = slots + (size_t)(it & 1) * 131072 + rd_in;
    i32x4 sl_[8][2];
    for (;;) {
      #pragma unroll
      for (int ks = 0; ks < 8; ++ks) {
        ld16_cc(&sl_[ks][0], rp + ks * 8192);
        ld16_cc(&sl_[ks][1], rp + ks * 8192 + 1024);
      }
      asm volatile("s_waitcnt vmcnt(0)" ::: "memory");
      __builtin_amdgcn_sched_barrier(0);
      int ok = 1;
      #pragma unroll
      for (int ks = 0; ks < 8; ++ks)
        ok &= (sl_[ks][0][2] == it) & (sl_[ks][1][2] == it);
      if (__all(ok)) break;
      __builtin_amdgcn_s_sleep(1);
    }
    #pragma unroll
    for (int ks = 0; ks < 8; ++ks) {
      i32x4 t;
      t[0] = sl_[ks][0][0]; t[1] = sl_[ks][0][1];
      t[2] = sl_[ks][1][0]; t[3] = sl_[ks][1][1];
      bf16x8 a = __builtin_bit_cast(bf16x8, t);
      acc0 = __builtin_amdgcn_mfma_f32_16x16x32_bf16(a, Bh[0][ks], acc0, 0, 0, 0);
      acc1 = __builtin_amdgcn_mfma_f32_16x16x32_bf16(a, Bh[1][ks], acc1, 0, 0, 0);
    }

    // --- K-half partial exchange via LDS (double-buffered, ONE barrier) ---
    #pragma unroll
    for (int r = 0; r < 4; ++r) {
      glds[it & 1][kh][16 * mt + 4 * kg + r][colp]     = acc0[r];
      glds[it & 1][kh][16 * mt + 4 * kg + r][colp + 4] = acc1[r];
    }
    __syncthreads();

    // --- finalize: lane owns (sglob, unit u); scalar cell state ---
    const float* g0 = &glds[it & 1][0][sglob][0];
    const float* g1 = &glds[it & 1][1][sglob][0];
    float gi = g0[u]      + g1[u]      + bi;
    float gf = g0[u + 8]  + g1[u + 8]  + bf_;
    float gg = g0[u + 16] + g1[u + 16] + bg;
    float go = g0[u + 24] + g1[u + 24] + bo;
    float ig = sigm(gi);
    float fg = sigm(gf);
    float gt = tanh_fast(gg);
    float og = sigm(go);
    cstate = fg * cstate + ig * gt;
    float h = og * tanh_fast(cstate);

    if (it != SS - 1) {
      // pack 4 units into 8B + tag, single 16B atomic store per 4-unit half
      int hv  = (int)f2bf(h);
      int o1  = __shfl_xor(hv, 1, 64);
      int pk  = (hv & 0xffff) | (o1 << 16);          // units {u,u+1} on even u
      int pk2 = __shfl_xor(pk, 2, 64);               // units {u+2,u+3} on u%4==0
      if ((u & 3) == 0) {
        i32x4 val; val[0] = pk; val[1] = pk2; val[2] = it + 1; val[3] = 0;
        st16_cc(wr_base + (size_t)((it + 1) & 1) * 131072, val);
      }
    } else {
      hT[(size_t)sglob * HH + (p << 3) + u] = h;
    }
  }
}

// ---- phase 2: y[b] = hT[b,:] . Wout + bout ----
__global__ void outproj_kernel(const float* __restrict__ hT,
                               const float* __restrict__ Wout,
                               const float* __restrict__ bout,
                               float* __restrict__ y) {
  int b = blockIdx.x;
  int t = threadIdx.x;   // 64
  float s = 0.f;
  for (int j = t; j < HH; j += 64) s += hT[b * HH + j] * Wout[j];
  #pragma unroll
  for (int off = 32; off > 0; off >>= 1) s += __shfl_down(s, off, 64);
  if (t == 0) y[b] = s + bout[0];
}

extern "C" void kernel_launch(void* const* d_in, const int* in_sizes, int n_in,
                              void* d_out, int out_size, void* d_ws, size_t ws_size,
                              hipStream_t stream) {
  const int*   idx  = (const int*)d_in[0];
  const float* emb  = (const float*)d_in[1];
  const float* Wih  = (const float*)d_in[2];
  const float* Whh  = (const float*)d_in[3];
  const float* bih  = (const float*)d_in[4];
  const float* bhh  = (const float*)d_in[5];
  const float* Wout = (const float*)d_in[6];
  const float* bout = (const float*)d_in[7];
  float* y = (float*)d_out;

  char* ws = (char*)d_ws;
  unsigned short* xt = (unsigned short*)(ws + XT_OFF);
  char* slots        = ws + SLOT_OFF;
  float* hT          = (float*)(ws + HT_OFF);

  // deterministic per-call init: BOTH slot planes zeroed (h(0)=0, tags=0;
  // also kills stale tags from the previous graph replay)
  hipMemsetAsync(slots, 0, SLOT_BYTES, stream);

  gather_cast_kernel<<<SS * 4, 256, 0, stream>>>(idx, emb, xt);
  lstm_kernel<<<64, 512, 0, stream>>>(xt, slots, hT, Wih, Whh, bih, bhh);
  outproj_kernel<<<BB, 64, 0, stream>>>(hT, Wout, bout, y);
}